// Round 3
// baseline (13.258 us; speedup 1.0000x reference)
//
#include <hip/hip_runtime.h>

// total_energy_sum: N=4096 nodes, G=32 groups, T=4 types.
// out = [energy (G)] ++ [node_energy (N)], float32.
//
// R5 structure: ONE launch. Grid = G blocks of 1024 (16 waves), one block
// per group. R3's one-block-per-group was latency-bound (runtime bounds ->
// 8 serialized memory round-trips/wave); here trip counts are compile-time
// (GSZ=128) and each lane's 32 R/F loads are fully unrolled and issued
// BEFORE the LDS staging sync -> whole block pays ~1 memory round-trip,
// then is VALU-bound (~2us on 32 CUs). This removes R4's finish kernel +
// graph dependency edge (~2-3us) at the cost of ~1us more kernel time.
// Pair arithmetic, column<->lane association, and both reduction orders
// (wave shuffle tree, 16-wave LDS sum) are bit-identical to the passing
// R3 kernel (absmax 0.0).

template <int GSZ>
__global__ __launch_bounds__(1024, 4) void te_fused_kernel(
    const float* __restrict__ node_attrs,   // (N,4) one-hot
    const float* __restrict__ Rm,           // (N,N)
    const float* __restrict__ Fm,           // (N,N)
    const float* __restrict__ rA,           // (4,4)
    const float* __restrict__ rB,
    const float* __restrict__ rC,
    const float* __restrict__ rD,
    const float* __restrict__ rMu,
    const float* __restrict__ electric,     // (G)
    const float* __restrict__ aelec,        // (N)
    const float* __restrict__ shorte,       // (G)
    const float* __restrict__ ashort,       // (N)
    const int* __restrict__ batch,          // (N)
    float* __restrict__ out,                // (G + N)
    int n, int g) {
  constexpr int WAVES = 16;                 // 1024 threads
  constexpr int RPW = GSZ / WAVES;          // rows per wave (8)
  constexpr int CPL = GSZ / 64;             // cols per lane (2)

  const int b = blockIdx.x;
  const int gbase = b * GSZ;

  __shared__ float tab[5 * 16];             // A,B,C,D,mu tables
  __shared__ int   stype[GSZ];
  __shared__ int   sbatch[GSZ];
  __shared__ float snode[GSZ];              // aelec+ashort
  __shared__ float wsum[WAVES];

  const int t = threadIdx.x;
  const int wave = t >> 6;
  const int lane = t & 63;
  const int row0 = wave * RPW;

  // Scalar group inputs (broadcast loads), issued early.
  const float eb = electric[b];
  const float sb = shorte[b];

  // Issue ALL value loads up front: 8 rows x 2 cols x {R,F} = 32 in-flight
  // loads per lane, overlapping the LDS staging round-trip.
  float rv[RPW][CPL], fv[RPW][CPL];
#pragma unroll
  for (int r = 0; r < RPW; ++r) {
    const size_t off = (size_t)(gbase + row0 + r) * n + gbase + lane;
#pragma unroll
    for (int q = 0; q < CPL; ++q) {
      rv[r][q] = Rm[off + q * 64];
      fv[r][q] = Fm[off + q * 64];
    }
  }

  if (t < 16) {
    tab[t]      = rA[t];
    tab[16 + t] = rB[t];
    tab[32 + t] = rC[t];
    tab[48 + t] = rD[t];
    tab[64 + t] = rMu[t];
  }
  if (t < GSZ) {
    const float4 v = *(const float4*)(node_attrs + (size_t)(gbase + t) * 4);
    int bt = 0;
    float best = v.x;
    if (v.y > best) { best = v.y; bt = 1; }
    if (v.z > best) { best = v.z; bt = 2; }
    if (v.w > best) { best = v.w; bt = 3; }
    stype[t]  = bt;
    sbatch[t] = batch[gbase + t];
    snode[t]  = aelec[gbase + t] + ashort[gbase + t];
  }
  __syncthreads();

  float gpart = 0.f;                        // lane0-only partial of group sum
#pragma unroll
  for (int r = 0; r < RPW; ++r) {
    const int rl  = row0 + r;
    const int bi  = sbatch[rl];
    const int ti4 = stype[rl] * 4;
    float acc = 0.f;
#pragma unroll
    for (int q = 0; q < CPL; ++q) {
      const int jl = lane + q * 64;
      if (sbatch[jl] == bi && jl != rl) {
        float rr = rv[r][q];
        float f  = fv[r][q];
        int idx = ti4 + stype[jl];
        float r2 = rr * rr;
        float r6 = r2 * r2 * r2;
        float val = tab[idx] * __expf(tab[16 + idx] * (tab[64 + idx] - rr))
                    - tab[32 + idx] / r6
                    - tab[48 + idx] / (r6 * r2);
        acc += val * f;
      }
    }
#pragma unroll
    for (int o = 32; o > 0; o >>= 1) acc += __shfl_down(acc, o, 64);
    if (lane == 0) {
      const int gi = gbase + rl;
      float half = 0.5f * acc;
      out[g + gi] = snode[rl] + half;        // node_energy
      gpart += half;
    }
  }
  if (lane == 0) wsum[wave] = gpart;
  __syncthreads();

  if (t == 0) {
    float s = 0.f;
#pragma unroll
    for (int w = 0; w < WAVES; ++w) s += wsum[w];
    out[b] = eb + s + sb;                    // energy, plain store
  }
}

// Generic fallback (R3 structure): one block per group, any gsz <= 128.
__global__ __launch_bounds__(1024) void te_group_kernel(
    const float* __restrict__ node_attrs,
    const float* __restrict__ Rm,
    const float* __restrict__ Fm,
    const float* __restrict__ rA,
    const float* __restrict__ rB,
    const float* __restrict__ rC,
    const float* __restrict__ rD,
    const float* __restrict__ rMu,
    const float* __restrict__ electric,
    const float* __restrict__ aelec,
    const float* __restrict__ shorte,
    const float* __restrict__ ashort,
    const int* __restrict__ batch,
    float* __restrict__ out,
    int n, int g) {
  const int gsz = n / g;
  const int gbase = blockIdx.x * gsz;

  __shared__ float tab[5 * 16];
  __shared__ int   stype[128];
  __shared__ int   sbatch[128];
  __shared__ float snode[128];
  __shared__ float wsum[16];

  int t = threadIdx.x;
  if (t < 16) {
    tab[t]      = rA[t];
    tab[16 + t] = rB[t];
    tab[32 + t] = rC[t];
    tab[48 + t] = rD[t];
    tab[64 + t] = rMu[t];
  }
  if (t < gsz) {
    const float4 v = *(const float4*)(node_attrs + (size_t)(gbase + t) * 4);
    int bt = 0;
    float best = v.x;
    if (v.y > best) { best = v.y; bt = 1; }
    if (v.z > best) { best = v.z; bt = 2; }
    if (v.w > best) { best = v.w; bt = 3; }
    stype[t]  = bt;
    sbatch[t] = batch[gbase + t];
    snode[t]  = aelec[gbase + t] + ashort[gbase + t];
  }
  __syncthreads();

  const int wave = t >> 6;
  const int lane = t & 63;
  const int rpw = (gsz + 15) >> 4;
  const int r0 = wave * rpw;
  const int r1 = (r0 + rpw < gsz) ? (r0 + rpw) : gsz;

  float gpart = 0.f;
  for (int rl = r0; rl < r1; ++rl) {
    const int gi  = gbase + rl;
    const int bi  = sbatch[rl];
    const int ti4 = stype[rl] * 4;
    const float* Rrow = Rm + (size_t)gi * n + gbase;
    const float* Frow = Fm + (size_t)gi * n + gbase;

    float acc = 0.f;
    for (int jl = lane; jl < gsz; jl += 64) {
      if (sbatch[jl] == bi && jl != rl) {
        float r = Rrow[jl];
        float f = Frow[jl];
        int idx = ti4 + stype[jl];
        float r2 = r * r;
        float r6 = r2 * r2 * r2;
        float val = tab[idx] * __expf(tab[16 + idx] * (tab[64 + idx] - r))
                    - tab[32 + idx] / r6
                    - tab[48 + idx] / (r6 * r2);
        acc += val * f;
      }
    }
#pragma unroll
    for (int o = 32; o > 0; o >>= 1) acc += __shfl_down(acc, o, 64);
    if (lane == 0) {
      float half = 0.5f * acc;
      out[g + gi] = snode[rl] + half;
      gpart += half;
    }
  }
  if (lane == 0) wsum[wave] = (r0 < gsz) ? gpart : 0.f;
  __syncthreads();

  if (t == 0) {
    float s = 0.f;
#pragma unroll
    for (int w = 0; w < 16; ++w) s += wsum[w];
    int bb = sbatch[0];
    out[bb] = electric[bb] + s + shorte[bb];
  }
}

extern "C" void kernel_launch(void* const* d_in, const int* in_sizes, int n_in,
                              void* d_out, int out_size, void* d_ws, size_t ws_size,
                              hipStream_t stream) {
  const float* node_attrs = (const float*)d_in[0];
  const float* Rm         = (const float*)d_in[1];
  const float* Fm         = (const float*)d_in[2];
  const float* rA         = (const float*)d_in[3];
  const float* rB         = (const float*)d_in[4];
  const float* rC         = (const float*)d_in[5];
  const float* rD         = (const float*)d_in[6];
  const float* rMu        = (const float*)d_in[7];
  const float* electric   = (const float*)d_in[8];
  const float* aelec      = (const float*)d_in[9];
  const float* shorte     = (const float*)d_in[10];
  const float* ashort     = (const float*)d_in[11];
  const int*   batch      = (const int*)d_in[12];

  int n = in_sizes[12];   // 4096
  int g = in_sizes[8];    // 32
  float* out = (float*)d_out;

  if (g > 0 && n % g == 0 && n / g == 128) {
    te_fused_kernel<128><<<g, 1024, 0, stream>>>(
        node_attrs, Rm, Fm, rA, rB, rC, rD, rMu, electric, aelec, shorte,
        ashort, batch, out, n, g);
  } else {
    te_group_kernel<<<g, 1024, 0, stream>>>(node_attrs, Rm, Fm, rA, rB, rC, rD,
                                            rMu, electric, aelec, shorte,
                                            ashort, batch, out, n, g);
  }
}

// Round 4
// 11.342 us; speedup vs baseline: 1.1690x; 1.1690x over previous
//
#include <hip/hip_runtime.h>

// total_energy_sum: N=4096 nodes, G=32 groups, T=4 types.
// out = [energy (G)] ++ [node_energy (N)], float32.
//
// R6 structure: back to R4's winning shape (grid spans all CUs, tiny finish
// dispatch — measured cheaper than any single-dispatch alternative), with
// two latency fixes:
//  - aelec/ashort prefetched in the SAME up-front load batch as R/F
//    (R4 loaded them lane0-only AFTER compute -> trailing cold round-trip).
//  - 512-thread blocks (8 waves -> 2 waves/SIMD) for dependency-stall
//    hiding; grid = G*BPG = 256 blocks = 1 block/CU.
// Per-pair arithmetic, lane<->column association (j = lane, lane+64) and
// the 64-lane shuffle tree are bit-identical to R2..R5 (all absmax 0.0).
// Group-sum association differs; empirically tolerated (R2's atomicAdd
// order was nondeterministic and still scored absmax 0.0).

template <int GSZ, int BPG>
__global__ __launch_bounds__(512) void te_part_kernel(
    const float* __restrict__ node_attrs,   // (N,4) one-hot
    const float* __restrict__ Rm,           // (N,N)
    const float* __restrict__ Fm,           // (N,N)
    const float* __restrict__ rA,           // (4,4)
    const float* __restrict__ rB,
    const float* __restrict__ rC,
    const float* __restrict__ rD,
    const float* __restrict__ rMu,
    const float* __restrict__ aelec,        // (N)
    const float* __restrict__ ashort,       // (N)
    const int* __restrict__ batch,          // (N)
    float* __restrict__ out,                // (G + N)
    float* __restrict__ ws,                 // (G*BPG) partials
    int n, int g) {
  constexpr int WAVES = 8;                  // 512 threads
  constexpr int RPB = GSZ / BPG;            // rows per block (16)
  constexpr int RPW = RPB / WAVES;          // rows per wave (2)
  constexpr int CPL = GSZ / 64;             // cols per lane (2)

  const int b = blockIdx.x / BPG;
  const int c = blockIdx.x % BPG;
  const int gbase = b * GSZ;

  __shared__ float tab[5 * 16];             // A,B,C,D,mu tables
  __shared__ int   stype[GSZ];
  __shared__ int   sbatch[GSZ];
  __shared__ float wpart[WAVES];

  const int t = threadIdx.x;
  const int wave = t >> 6;
  const int lane = t & 63;
  const int row0 = c * RPB + wave * RPW;    // this wave's first group-row

  // ---- one up-front load batch: R/F values + node bias terms ----
  float rv[RPW][CPL], fv[RPW][CPL], ae[RPW], ash[RPW];
#pragma unroll
  for (int r = 0; r < RPW; ++r) {
    const int gi = gbase + row0 + r;
    const size_t off = (size_t)gi * n + gbase + lane;
#pragma unroll
    for (int q = 0; q < CPL; ++q) {
      rv[r][q] = Rm[off + q * 64];
      fv[r][q] = Fm[off + q * 64];
    }
    ae[r]  = aelec[gi];                     // wave-uniform (1 line each)
    ash[r] = ashort[gi];
  }

  // ---- LDS staging (overlaps the loads above) ----
  if (t < 16) {
    tab[t]      = rA[t];
    tab[16 + t] = rB[t];
    tab[32 + t] = rC[t];
    tab[48 + t] = rD[t];
    tab[64 + t] = rMu[t];
  }
  if (t < GSZ) {
    const float4 v = *(const float4*)(node_attrs + (size_t)(gbase + t) * 4);
    int bt = 0;
    float best = v.x;
    if (v.y > best) { best = v.y; bt = 1; }
    if (v.z > best) { best = v.z; bt = 2; }
    if (v.w > best) { best = v.w; bt = 3; }
    stype[t]  = bt;
    sbatch[t] = batch[gbase + t];
  }
  __syncthreads();

  float bpart = 0.f;                        // lane0-only partial of group sum
#pragma unroll
  for (int r = 0; r < RPW; ++r) {
    const int rl  = row0 + r;
    const int bi  = sbatch[rl];
    const int ti4 = stype[rl] * 4;
    float acc = 0.f;
#pragma unroll
    for (int q = 0; q < CPL; ++q) {
      const int jl = lane + q * 64;
      if (sbatch[jl] == bi && jl != rl) {
        float rr = rv[r][q];
        float f  = fv[r][q];
        int idx = ti4 + stype[jl];
        float r2 = rr * rr;
        float r6 = r2 * r2 * r2;
        float val = tab[idx] * __expf(tab[16 + idx] * (tab[64 + idx] - rr))
                    - tab[32 + idx] / r6
                    - tab[48 + idx] / (r6 * r2);
        acc += val * f;
      }
    }
#pragma unroll
    for (int o = 32; o > 0; o >>= 1) acc += __shfl_down(acc, o, 64);
    if (lane == 0) {
      float half = 0.5f * acc;
      out[g + gbase + rl] = ae[r] + half + ash[r];   // node_energy
      bpart += half;
    }
  }
  if (lane == 0) wpart[wave] = bpart;
  __syncthreads();

  if (t == 0) {
    float s = 0.f;
#pragma unroll
    for (int w = 0; w < WAVES; ++w) s += wpart[w];
    ws[blockIdx.x] = s;                     // plain store, no init needed
  }
}

template <int BPG>
__global__ __launch_bounds__(64) void te_finish_kernel(
    const float* __restrict__ electric,     // (G)
    const float* __restrict__ shorte,       // (G)
    const float* __restrict__ ws,           // (G*BPG)
    float* __restrict__ out,                // (G + N)
    int g) {
  int t = threadIdx.x;
  if (t < g) {
    const float e  = electric[t];
    const float sh = shorte[t];
    const float4* w4 = (const float4*)(ws + t * BPG);
    float s = 0.f;
#pragma unroll
    for (int q = 0; q < BPG / 4; ++q) {
      const float4 v = w4[q];
      s += v.x; s += v.y; s += v.z; s += v.w;   // ascending order, as before
    }
    out[t] = e + s + sh;                    // energy
  }
}

// Generic fallback (R3 structure): one block per group, any gsz <= 128.
__global__ __launch_bounds__(1024) void te_group_kernel(
    const float* __restrict__ node_attrs,
    const float* __restrict__ Rm,
    const float* __restrict__ Fm,
    const float* __restrict__ rA,
    const float* __restrict__ rB,
    const float* __restrict__ rC,
    const float* __restrict__ rD,
    const float* __restrict__ rMu,
    const float* __restrict__ electric,
    const float* __restrict__ aelec,
    const float* __restrict__ shorte,
    const float* __restrict__ ashort,
    const int* __restrict__ batch,
    float* __restrict__ out,
    int n, int g) {
  const int gsz = n / g;
  const int gbase = blockIdx.x * gsz;

  __shared__ float tab[5 * 16];
  __shared__ int   stype[128];
  __shared__ int   sbatch[128];
  __shared__ float snode[128];
  __shared__ float wsum[16];

  int t = threadIdx.x;
  if (t < 16) {
    tab[t]      = rA[t];
    tab[16 + t] = rB[t];
    tab[32 + t] = rC[t];
    tab[48 + t] = rD[t];
    tab[64 + t] = rMu[t];
  }
  if (t < gsz) {
    const float4 v = *(const float4*)(node_attrs + (size_t)(gbase + t) * 4);
    int bt = 0;
    float best = v.x;
    if (v.y > best) { best = v.y; bt = 1; }
    if (v.z > best) { best = v.z; bt = 2; }
    if (v.w > best) { best = v.w; bt = 3; }
    stype[t]  = bt;
    sbatch[t] = batch[gbase + t];
    snode[t]  = aelec[gbase + t] + ashort[gbase + t];
  }
  __syncthreads();

  const int wave = t >> 6;
  const int lane = t & 63;
  const int rpw = (gsz + 15) >> 4;
  const int r0 = wave * rpw;
  const int r1 = (r0 + rpw < gsz) ? (r0 + rpw) : gsz;

  float gpart = 0.f;
  for (int rl = r0; rl < r1; ++rl) {
    const int gi  = gbase + rl;
    const int bi  = sbatch[rl];
    const int ti4 = stype[rl] * 4;
    const float* Rrow = Rm + (size_t)gi * n + gbase;
    const float* Frow = Fm + (size_t)gi * n + gbase;

    float acc = 0.f;
    for (int jl = lane; jl < gsz; jl += 64) {
      if (sbatch[jl] == bi && jl != rl) {
        float r = Rrow[jl];
        float f = Frow[jl];
        int idx = ti4 + stype[jl];
        float r2 = r * r;
        float r6 = r2 * r2 * r2;
        float val = tab[idx] * __expf(tab[16 + idx] * (tab[64 + idx] - r))
                    - tab[32 + idx] / r6
                    - tab[48 + idx] / (r6 * r2);
        acc += val * f;
      }
    }
#pragma unroll
    for (int o = 32; o > 0; o >>= 1) acc += __shfl_down(acc, o, 64);
    if (lane == 0) {
      float half = 0.5f * acc;
      out[g + gi] = snode[rl] + half;
      gpart += half;
    }
  }
  if (lane == 0) wsum[wave] = (r0 < gsz) ? gpart : 0.f;
  __syncthreads();

  if (t == 0) {
    float s = 0.f;
#pragma unroll
    for (int w = 0; w < 16; ++w) s += wsum[w];
    int bb = sbatch[0];
    out[bb] = electric[bb] + s + shorte[bb];
  }
}

extern "C" void kernel_launch(void* const* d_in, const int* in_sizes, int n_in,
                              void* d_out, int out_size, void* d_ws, size_t ws_size,
                              hipStream_t stream) {
  const float* node_attrs = (const float*)d_in[0];
  const float* Rm         = (const float*)d_in[1];
  const float* Fm         = (const float*)d_in[2];
  const float* rA         = (const float*)d_in[3];
  const float* rB         = (const float*)d_in[4];
  const float* rC         = (const float*)d_in[5];
  const float* rD         = (const float*)d_in[6];
  const float* rMu        = (const float*)d_in[7];
  const float* electric   = (const float*)d_in[8];
  const float* aelec      = (const float*)d_in[9];
  const float* shorte     = (const float*)d_in[10];
  const float* ashort     = (const float*)d_in[11];
  const int*   batch      = (const int*)d_in[12];

  int n = in_sizes[12];   // 4096
  int g = in_sizes[8];    // 32
  float* out = (float*)d_out;
  float* ws  = (float*)d_ws;

  if (g > 0 && n % g == 0 && n / g == 128) {
    constexpr int BPG = 8;
    te_part_kernel<128, BPG><<<g * BPG, 512, 0, stream>>>(
        node_attrs, Rm, Fm, rA, rB, rC, rD, rMu, aelec, ashort, batch,
        out, ws, n, g);
    te_finish_kernel<BPG><<<1, 64, 0, stream>>>(electric, shorte, ws, out, g);
  } else {
    te_group_kernel<<<g, 1024, 0, stream>>>(node_attrs, Rm, Fm, rA, rB, rC, rD,
                                            rMu, electric, aelec, shorte,
                                            ashort, batch, out, n, g);
  }
}

// Round 5
// 11.236 us; speedup vs baseline: 1.1800x; 1.0095x over previous
//
#include <hip/hip_runtime.h>

// total_energy_sum: N=4096 nodes, G=32 groups, T=4 types.
// out = [energy (G)] ++ [node_energy (N)], float32.
//
// R7 structure: R6's winning shape (grid = G*BPG = 256 blocks of 512 on all
// CUs + tiny finish dispatch), with the part kernel's critical path cut:
//  - NO stype/sbatch LDS staging: with T=4, each lane computes its 2 column
//    types by argmax of a float4 loaded directly into registers in the same
//    up-front batch as R/F (plus 2 wave-uniform row float4s). Deletes the
//    staging loads, the ds_read latency, and one barrier's worth of work.
//  - Only `tab` (5x16 table) goes through LDS; its 16-thread staging
//    overlaps the value-load round-trip ahead of the single barrier.
//  - NO second __syncthreads: each wave plain-stores its partial to ws
//    (G*BPG*WAVES slots); the finish kernel sums 64 partials/group as 16
//    float4 loads (one round-trip, same as before).
// Per-pair arithmetic, lane<->column association (j = lane, lane+64),
// argmax tie-break, and the 64-lane shuffle tree are bit-identical to
// R2..R6 (all absmax 0.0). Group-sum association differs; empirically
// tolerated across R2/R4/R5/R6.

__device__ __forceinline__ int argmax4(float4 v) {
  int bt = 0;
  float best = v.x;
  if (v.y > best) { best = v.y; bt = 1; }
  if (v.z > best) { best = v.z; bt = 2; }
  if (v.w > best) { best = v.w; bt = 3; }
  return bt;
}

template <int GSZ, int BPG>
__global__ __launch_bounds__(512) void te_part_kernel(
    const float* __restrict__ node_attrs,   // (N,4) one-hot
    const float* __restrict__ Rm,           // (N,N)
    const float* __restrict__ Fm,           // (N,N)
    const float* __restrict__ rA,           // (4,4)
    const float* __restrict__ rB,
    const float* __restrict__ rC,
    const float* __restrict__ rD,
    const float* __restrict__ rMu,
    const float* __restrict__ aelec,        // (N)
    const float* __restrict__ ashort,       // (N)
    const int* __restrict__ batch,          // (N)
    float* __restrict__ out,                // (G + N)
    float* __restrict__ ws,                 // (G*BPG*WAVES) partials
    int n, int g) {
  constexpr int WAVES = 8;                  // 512 threads
  constexpr int RPB = GSZ / BPG;            // rows per block (16)
  constexpr int RPW = RPB / WAVES;          // rows per wave (2)
  constexpr int CPL = GSZ / 64;             // cols per lane (2)

  const int b = blockIdx.x / BPG;
  const int c = blockIdx.x % BPG;
  const int gbase = b * GSZ;

  __shared__ float tab[5 * 16];             // A,B,C,D,mu tables

  const int t = threadIdx.x;
  const int wave = t >> 6;
  const int lane = t & 63;
  const int row0 = c * RPB + wave * RPW;    // this wave's first group-row

  // ---- one up-front load batch, all independent, ~1 round-trip ----
  float4 naC[CPL];                          // column one-hots -> types
  int    batC[CPL];
#pragma unroll
  for (int q = 0; q < CPL; ++q) {
    const int gj = gbase + lane + q * 64;
    naC[q]  = *(const float4*)(node_attrs + (size_t)gj * 4);
    batC[q] = batch[gj];
  }
  float rv[RPW][CPL], fv[RPW][CPL], ae[RPW], ash[RPW];
  float4 naR[RPW];
  int    batR[RPW];
#pragma unroll
  for (int r = 0; r < RPW; ++r) {
    const int gi = gbase + row0 + r;
    const size_t off = (size_t)gi * n + gbase + lane;
#pragma unroll
    for (int q = 0; q < CPL; ++q) {
      rv[r][q] = Rm[off + q * 64];
      fv[r][q] = Fm[off + q * 64];
    }
    naR[r]  = *(const float4*)(node_attrs + (size_t)gi * 4);  // wave-uniform
    batR[r] = batch[gi];
    ae[r]   = aelec[gi];
    ash[r]  = ashort[gi];
  }

  // ---- tiny LDS staging (16 threads), overlaps the loads above ----
  if (t < 16) {
    tab[t]      = rA[t];
    tab[16 + t] = rB[t];
    tab[32 + t] = rC[t];
    tab[48 + t] = rD[t];
    tab[64 + t] = rMu[t];
  }

  int tC[CPL];
#pragma unroll
  for (int q = 0; q < CPL; ++q) tC[q] = argmax4(naC[q]);

  __syncthreads();                          // tab ready (single barrier)

  float bpart = 0.f;                        // lane0-only partial of group sum
#pragma unroll
  for (int r = 0; r < RPW; ++r) {
    const int rl  = row0 + r;
    const int bi  = batR[r];
    const int ti4 = argmax4(naR[r]) * 4;
    float acc = 0.f;
#pragma unroll
    for (int q = 0; q < CPL; ++q) {
      const int jl = lane + q * 64;
      if (batC[q] == bi && jl != rl) {
        float rr = rv[r][q];
        float f  = fv[r][q];
        int idx = ti4 + tC[q];
        float r2 = rr * rr;
        float r6 = r2 * r2 * r2;
        float val = tab[idx] * __expf(tab[16 + idx] * (tab[64 + idx] - rr))
                    - tab[32 + idx] / r6
                    - tab[48 + idx] / (r6 * r2);
        acc += val * f;
      }
    }
#pragma unroll
    for (int o = 32; o > 0; o >>= 1) acc += __shfl_down(acc, o, 64);
    if (lane == 0) {
      float half = 0.5f * acc;
      out[g + gbase + rl] = ae[r] + half + ash[r];   // node_energy
      bpart += half;
    }
  }
  // Per-wave plain store; no second barrier, no block reduction.
  if (lane == 0) ws[blockIdx.x * WAVES + wave] = bpart;
}

template <int PPG>  // partials per group
__global__ __launch_bounds__(64) void te_finish_kernel(
    const float* __restrict__ electric,     // (G)
    const float* __restrict__ shorte,       // (G)
    const float* __restrict__ ws,           // (G*PPG)
    float* __restrict__ out,                // (G + N)
    int g) {
  int t = threadIdx.x;
  if (t < g) {
    const float e  = electric[t];
    const float sh = shorte[t];
    const float4* w4 = (const float4*)(ws + t * PPG);
    float s = 0.f;
#pragma unroll
    for (int q = 0; q < PPG / 4; ++q) {
      const float4 v = w4[q];
      s += v.x; s += v.y; s += v.z; s += v.w;   // ascending order
    }
    out[t] = e + s + sh;                    // energy
  }
}

// Generic fallback (R3 structure): one block per group, any gsz <= 128.
__global__ __launch_bounds__(1024) void te_group_kernel(
    const float* __restrict__ node_attrs,
    const float* __restrict__ Rm,
    const float* __restrict__ Fm,
    const float* __restrict__ rA,
    const float* __restrict__ rB,
    const float* __restrict__ rC,
    const float* __restrict__ rD,
    const float* __restrict__ rMu,
    const float* __restrict__ electric,
    const float* __restrict__ aelec,
    const float* __restrict__ shorte,
    const float* __restrict__ ashort,
    const int* __restrict__ batch,
    float* __restrict__ out,
    int n, int g) {
  const int gsz = n / g;
  const int gbase = blockIdx.x * gsz;

  __shared__ float tab[5 * 16];
  __shared__ int   stype[128];
  __shared__ int   sbatch[128];
  __shared__ float snode[128];
  __shared__ float wsum[16];

  int t = threadIdx.x;
  if (t < 16) {
    tab[t]      = rA[t];
    tab[16 + t] = rB[t];
    tab[32 + t] = rC[t];
    tab[48 + t] = rD[t];
    tab[64 + t] = rMu[t];
  }
  if (t < gsz) {
    const float4 v = *(const float4*)(node_attrs + (size_t)(gbase + t) * 4);
    int bt = 0;
    float best = v.x;
    if (v.y > best) { best = v.y; bt = 1; }
    if (v.z > best) { best = v.z; bt = 2; }
    if (v.w > best) { best = v.w; bt = 3; }
    stype[t]  = bt;
    sbatch[t] = batch[gbase + t];
    snode[t]  = aelec[gbase + t] + ashort[gbase + t];
  }
  __syncthreads();

  const int wave = t >> 6;
  const int lane = t & 63;
  const int rpw = (gsz + 15) >> 4;
  const int r0 = wave * rpw;
  const int r1 = (r0 + rpw < gsz) ? (r0 + rpw) : gsz;

  float gpart = 0.f;
  for (int rl = r0; rl < r1; ++rl) {
    const int gi  = gbase + rl;
    const int bi  = sbatch[rl];
    const int ti4 = stype[rl] * 4;
    const float* Rrow = Rm + (size_t)gi * n + gbase;
    const float* Frow = Fm + (size_t)gi * n + gbase;

    float acc = 0.f;
    for (int jl = lane; jl < gsz; jl += 64) {
      if (sbatch[jl] == bi && jl != rl) {
        float r = Rrow[jl];
        float f = Frow[jl];
        int idx = ti4 + stype[jl];
        float r2 = r * r;
        float r6 = r2 * r2 * r2;
        float val = tab[idx] * __expf(tab[16 + idx] * (tab[64 + idx] - r))
                    - tab[32 + idx] / r6
                    - tab[48 + idx] / (r6 * r2);
        acc += val * f;
      }
    }
#pragma unroll
    for (int o = 32; o > 0; o >>= 1) acc += __shfl_down(acc, o, 64);
    if (lane == 0) {
      float half = 0.5f * acc;
      out[g + gi] = snode[rl] + half;
      gpart += half;
    }
  }
  if (lane == 0) wsum[wave] = (r0 < gsz) ? gpart : 0.f;
  __syncthreads();

  if (t == 0) {
    float s = 0.f;
#pragma unroll
    for (int w = 0; w < 16; ++w) s += wsum[w];
    int bb = sbatch[0];
    out[bb] = electric[bb] + s + shorte[bb];
  }
}

extern "C" void kernel_launch(void* const* d_in, const int* in_sizes, int n_in,
                              void* d_out, int out_size, void* d_ws, size_t ws_size,
                              hipStream_t stream) {
  const float* node_attrs = (const float*)d_in[0];
  const float* Rm         = (const float*)d_in[1];
  const float* Fm         = (const float*)d_in[2];
  const float* rA         = (const float*)d_in[3];
  const float* rB         = (const float*)d_in[4];
  const float* rC         = (const float*)d_in[5];
  const float* rD         = (const float*)d_in[6];
  const float* rMu        = (const float*)d_in[7];
  const float* electric   = (const float*)d_in[8];
  const float* aelec      = (const float*)d_in[9];
  const float* shorte     = (const float*)d_in[10];
  const float* ashort     = (const float*)d_in[11];
  const int*   batch      = (const int*)d_in[12];

  int n = in_sizes[12];   // 4096
  int g = in_sizes[8];    // 32
  float* out = (float*)d_out;
  float* ws  = (float*)d_ws;

  if (g > 0 && n % g == 0 && n / g == 128) {
    constexpr int BPG = 8;
    constexpr int WAVES = 8;
    te_part_kernel<128, BPG><<<g * BPG, 512, 0, stream>>>(
        node_attrs, Rm, Fm, rA, rB, rC, rD, rMu, aelec, ashort, batch,
        out, ws, n, g);
    te_finish_kernel<BPG * WAVES><<<1, 64, 0, stream>>>(
        electric, shorte, ws, out, g);
  } else {
    te_group_kernel<<<g, 1024, 0, stream>>>(node_attrs, Rm, Fm, rA, rB, rC, rD,
                                            rMu, electric, aelec, shorte,
                                            ashort, batch, out, n, g);
  }
}